// Round 11
// baseline (778.327 us; speedup 1.0000x reference)
//
#include <hip/hip_runtime.h>
#include <math.h>

// Problem constants
#define NI 1152
#define NO 32
#define DI 32
#define DO 32
#define NBATCH 128

constexpr int IBLK = 36;                 // i's per block
constexpr int NIB  = 32;                 // i-blocks
constexpr int BBLK = 16;                 // batches per block
constexpr int NBB  = NBATCH / BBLK;      // 8

typedef __attribute__((ext_vector_type(8))) short short8v;
typedef __attribute__((ext_vector_type(4))) float f32x4;
typedef __attribute__((ext_vector_type(2))) float f32x2;

#define BARLDS() do { asm volatile("s_waitcnt lgkmcnt(0)" ::: "memory"); \
  __builtin_amdgcn_sched_barrier(0); __builtin_amdgcn_s_barrier(); } while (0)

// 3-way truncation split: w = hi + mid + lo (bf16 each), residual <= 2^-23|w|.
struct S3 { short hi, mi, lo; };
__device__ __forceinline__ S3 split3(float w) {
  S3 r;
  const unsigned u = __float_as_uint(w);
  r.hi = (short)(u >> 16);
  const float r1 = w - __uint_as_float(u & 0xFFFF0000u);
  const unsigned r1u = __float_as_uint(r1);
  r.mi = (short)(r1u >> 16);
  const float r2 = r1 - __uint_as_float(r1u & 0xFFFF0000u);
  r.lo = (short)(__float_as_uint(r2) >> 16);
  return r;
}

// ============ FAST PATH v3: IDENTITY planes + direct fragment loads =========

// Identity pack: plane short index j holds limb of Wg flat float index j.
// Each thread handles 8 consecutive values (one short8v store per plane).
__global__ __launch_bounds__(256)
void caps_pack3(const float* __restrict__ Wg, short8v* __restrict__ P0,
                short8v* __restrict__ P1, short8v* __restrict__ P2)
{
  const size_t j8 = (size_t)blockIdx.x * 256 + threadIdx.x;
  const float* src = Wg + j8 * 8;
  const f32x4 a = *(const f32x4*)src;
  const f32x4 b = *(const f32x4*)(src + 4);
  short8v hi, mi, lo;
#pragma unroll
  for (int e = 0; e < 4; ++e) {
    S3 r0 = split3(a[e]); hi[e] = r0.hi;     mi[e] = r0.mi;     lo[e] = r0.lo;
    S3 r1 = split3(b[e]); hi[4 + e] = r1.hi; mi[4 + e] = r1.mi; lo[4 + e] = r1.lo;
  }
  P0[j8] = hi;
  P1[j8] = mi;
  P2[j8] = lo;
}

// Round-6 pass semantics; W fragments loaded directly from identity planes.
// Lane l of tile tl holds W[i][od = w*128 + tl*16 + (l&15)][k = (l>>4)*8 + e]
// -> short8v index = i*4096 + od*4 + (l>>4)  (the r6-verified mapping).
//  IT==0: c = 1/32 uniform (post-MFMA), accumulate s0 partials, no barriers.
//  IT==1: logits = sum_d x_hat*v0 ; write to bbuf ; softmax ; s1 partials.
//  IT==2: logits = bbuf + sum_d x_hat*v1 ; softmax ; s2 partials.
template<int IT>
__global__ __launch_bounds__(512, 2)
void caps_passd(const float* __restrict__ xg, const short8v* __restrict__ P0,
                const short8v* __restrict__ P1, const short8v* __restrict__ P2,
                float* __restrict__ spart, const float* __restrict__ s_in,
                const float* __restrict__ fsc, float* __restrict__ bbuf)
{
  __shared__ float bl[16 * 32];

  const int t = threadIdx.x, w = t >> 6, l = t & 63;
  const int ib = blockIdx.x, bb = blockIdx.y, b0 = bb * BBLK;

  // x fragment source: x[b = l&15][k = (l>>4)*8 + e]
  const float* xbase = xg + (size_t)(b0 + (l & 15)) * (NI * DI) + (l >> 4) * 8;

  // per-lane W fragment base (short8v units), tile stride = 64
  const size_t wbase = (size_t)(w * 128 + (l & 15)) * 4 + (l >> 4);

  // v fragments (IT>0): v = f * s_in, fragment-natural flat layout
  f32x4 vfrag[8];
  if constexpr (IT > 0) {
    const float f = fsc[0];
    const float* vp = s_in + (size_t)bb * 16384 + w * 2048 + l * 4;
#pragma unroll
    for (int tl = 0; tl < 8; ++tl) {
      f32x4 sv = *(const f32x4*)(vp + tl * 256);
      vfrag[tl] = sv * f;
    }
  }

  f32x4 sreg[8];
#pragma unroll
  for (int tl = 0; tl < 8; ++tl) sreg[tl] = (f32x4){0.f, 0.f, 0.f, 0.f};

  const int i0 = ib * IBLK;

  for (int ii = 0; ii < IBLK; ++ii) {
    const int i = i0 + ii;

    // x load + 3-limb split (r6 verbatim)
    const f32x4 xa = *(const f32x4*)(xbase + (size_t)i * DI);
    const f32x4 xb = *(const f32x4*)(xbase + (size_t)i * DI + 4);
    short8v xhi, xmi, xlo;
#pragma unroll
    for (int e = 0; e < 4; ++e) {
      S3 r0 = split3(xa[e]);
      xhi[e] = r0.hi; xmi[e] = r0.mi; xlo[e] = r0.lo;
      S3 r1 = split3(xb[e]);
      xhi[4 + e] = r1.hi; xmi[4 + e] = r1.mi; xlo[4 + e] = r1.lo;
    }

    f32x4 acc[8];
#pragma unroll
    for (int tl = 0; tl < 8; ++tl) acc[tl] = (f32x4){0.f, 0.f, 0.f, 0.f};

    const size_t pb = (size_t)i * 4096 + wbase;
#pragma unroll
    for (int tl = 0; tl < 8; ++tl) {
      const size_t widx = pb + (size_t)tl * 64;
      const short8v wh = P0[widx];
      const short8v wm = P1[widx];
      const short8v wo = P2[widx];
      f32x4 a = acc[tl];
      a = __builtin_amdgcn_mfma_f32_16x16x32_bf16(wh, xhi, a, 0, 0, 0);
      a = __builtin_amdgcn_mfma_f32_16x16x32_bf16(wh, xmi, a, 0, 0, 0);
      a = __builtin_amdgcn_mfma_f32_16x16x32_bf16(wm, xhi, a, 0, 0, 0);
      a = __builtin_amdgcn_mfma_f32_16x16x32_bf16(wh, xlo, a, 0, 0, 0);
      a = __builtin_amdgcn_mfma_f32_16x16x32_bf16(wo, xhi, a, 0, 0, 0);
      a = __builtin_amdgcn_mfma_f32_16x16x32_bf16(wm, xmi, a, 0, 0, 0);
      acc[tl] = a;
    }

    // ---- routing: r6 verbatim ----
    if constexpr (IT == 0) {
#pragma unroll
      for (int tl = 0; tl < 8; ++tl) sreg[tl] += acc[tl] * 0.03125f;
    } else {
      float bup[4];
#pragma unroll
      for (int j = 0; j < 4; ++j) {
        f32x4 p = acc[2 * j] * vfrag[2 * j] + acc[2 * j + 1] * vfrag[2 * j + 1];
        float v = p[0] + p[1] + p[2] + p[3];
        v += __shfl_xor(v, 16);
        v += __shfl_xor(v, 32);
        bup[j] = v;
      }
      if (l < 16) {
#pragma unroll
        for (int j = 0; j < 4; ++j) bl[l * 32 + w * 4 + j] = bup[j];
      }
      BARLDS();
      {  // softmax over o: thread -> (b = t>>5, o = t&31)
        const int bo = t >> 5, oo = t & 31;
        float lg = bl[bo * 32 + oo];
        if constexpr (IT == 2)
          lg += bbuf[(size_t)(b0 + bo) * (NI * NO) + (size_t)i * NO + oo];
        if constexpr (IT == 1)
          bbuf[(size_t)(b0 + bo) * (NI * NO) + (size_t)i * NO + oo] = lg;
        float mx = lg;
#pragma unroll
        for (int m = 1; m < 32; m <<= 1) mx = fmaxf(mx, __shfl_xor(mx, m));
        const float e = __expf(lg - mx);
        float sm = e;
#pragma unroll
        for (int m = 1; m < 32; m <<= 1) sm += __shfl_xor(sm, m);
        bl[bo * 32 + oo] = e / sm;
      }
      BARLDS();
#pragma unroll
      for (int j = 0; j < 4; ++j) {
        const float cj = bl[(l & 15) * 32 + w * 4 + j];
        sreg[2 * j]     += acc[2 * j]     * cj;
        sreg[2 * j + 1] += acc[2 * j + 1] * cj;
      }
    }
  }

  // flush partials (flat fragment layout, coalesced float4)
  {
    float* op = spart + ((size_t)ib * NBB + bb) * 16384 + w * 2048 + l * 4;
#pragma unroll
    for (int tl = 0; tl < 8; ++tl) *(f32x4*)(op + tl * 256) = sreg[tl];
  }
}

// ======================= SLOW PATH (round-6, proven) ========================

constexpr int LDS_FLOATS_S = 32 * 1024 + 16 * 32;

__device__ __forceinline__ void gll16(const float* g, float* l) {
  __builtin_amdgcn_global_load_lds(
      (const __attribute__((address_space(1))) void*)(const void*)g,
      (__attribute__((address_space(3))) void*)(void*)l, 16, 0, 0);
}

#define WAITV(n) do { asm volatile("s_waitcnt vmcnt(" #n ")" ::: "memory"); \
  __builtin_amdgcn_sched_barrier(0); } while (0)
#define LGKM0() do { asm volatile("s_waitcnt lgkmcnt(0)" ::: "memory"); \
  __builtin_amdgcn_sched_barrier(0); } while (0)

__device__ __forceinline__ void stage_w_half(const float* __restrict__ Wg,
                                             float* __restrict__ Wt,
                                             int i, int h, int w, size_t wsrc_lane) {
  const float* sb = Wg + (size_t)i * 32768 + wsrc_lane + (size_t)h * 2048;
  float* db = Wt + (size_t)(w * 1024 + h * 512) * 4;
#pragma unroll
  for (int r = 0; r < 8; ++r)
    gll16(sb + r * 256, db + r * 256);
}

template<int IT>
__global__ __launch_bounds__(512, 2)
void caps_pass_s(const float* __restrict__ xg, const float* __restrict__ Wg,
                 float* __restrict__ spart, const float* __restrict__ s_in,
                 const float* __restrict__ fsc, float* __restrict__ bbuf)
{
  extern __shared__ float lds[];
  float* Wt = lds;
  float* bl = lds + 32 * 1024;

  const int t = threadIdx.x, w = t >> 6, l = t & 63;
  const int ib = blockIdx.x, bb = blockIdx.y, b0 = bb * BBLK;

  const size_t wsrc_lane = (size_t)(w * 128 + (l >> 3)) * 32
                         + (size_t)(((l & 7) ^ (l >> 3)) * 4);
  int colf[4];
#pragma unroll
  for (int s = 0; s < 4; ++s)
    colf[s] = ((((l >> 4) * 2 + (s >> 1)) ^ (l & 7)) * 4) + (s & 1) * 2;

  const float* xbase = xg + (size_t)(b0 + (l & 15)) * (NI * DI) + (l >> 4) * 8;

  f32x4 vfrag[8];
  if constexpr (IT > 0) {
    const float f = fsc[0];
    const float* vp = s_in + (size_t)bb * 16384 + w * 2048 + l * 4;
#pragma unroll
    for (int tl = 0; tl < 8; ++tl) {
      f32x4 sv = *(const f32x4*)(vp + tl * 256);
      vfrag[tl] = sv * f;
    }
  }
  WAITV(0);

  f32x4 sreg[8];
#pragma unroll
  for (int tl = 0; tl < 8; ++tl) sreg[tl] = (f32x4){0.f, 0.f, 0.f, 0.f};

  const int i0 = ib * IBLK;
  stage_w_half(Wg, Wt, i0, 0, w, wsrc_lane);
  f32x4 xa = *(const f32x4*)(xbase + (size_t)i0 * DI);
  f32x4 xb = *(const f32x4*)(xbase + (size_t)i0 * DI + 4);
  stage_w_half(Wg, Wt, i0, 1, w, wsrc_lane);

  for (int ii = 0; ii < IBLK; ++ii) {
    const int i = i0 + ii;
    const int inext = i0 + ((ii + 1 < IBLK) ? ii + 1 : ii);

    f32x4 acc[8];
#pragma unroll
    for (int tl = 0; tl < 8; ++tl) acc[tl] = (f32x4){0.f, 0.f, 0.f, 0.f};

    short8v xhi, xmi, xlo;
    f32x4 xna, xnb;

#pragma unroll
    for (int h = 0; h < 2; ++h) {
      f32x2 wf[4][4];
      if (h == 0) {
        WAITV(8);
#pragma unroll
        for (int e = 0; e < 4; ++e) {
          S3 sa = split3(xa[e]);
          xhi[e] = sa.hi; xmi[e] = sa.mi; xlo[e] = sa.lo;
          S3 sb2 = split3(xb[e]);
          xhi[4 + e] = sb2.hi; xmi[4 + e] = sb2.mi; xlo[4 + e] = sb2.lo;
        }
      } else {
        WAITV(10);
      }
#pragma unroll
      for (int tl = 0; tl < 4; ++tl) {
        const float* rp = Wt + (size_t)(w * 128 + (h * 4 + tl) * 16 + (l & 15)) * 32;
#pragma unroll
        for (int s = 0; s < 4; ++s) wf[tl][s] = *(const f32x2*)(rp + colf[s]);
      }
      LGKM0();

      if (h == 0) {
        stage_w_half(Wg, Wt, inext, 0, w, wsrc_lane);
        xna = *(const f32x4*)(xbase + (size_t)inext * DI);
        xnb = *(const f32x4*)(xbase + (size_t)inext * DI + 4);
      } else {
        stage_w_half(Wg, Wt, inext, 1, w, wsrc_lane);
      }

#pragma unroll
      for (int tl = 0; tl < 4; ++tl) {
        const int tloc = h * 4 + tl;
        short8v whi, wmi, wlo;
#pragma unroll
        for (int s = 0; s < 4; ++s) {
          S3 s0 = split3(wf[tl][s].x);
          whi[2 * s] = s0.hi; wmi[2 * s] = s0.mi; wlo[2 * s] = s0.lo;
          S3 s1 = split3(wf[tl][s].y);
          whi[2 * s + 1] = s1.hi; wmi[2 * s + 1] = s1.mi; wlo[2 * s + 1] = s1.lo;
        }
        f32x4 a = acc[tloc];
        a = __builtin_amdgcn_mfma_f32_16x16x32_bf16(whi, xhi, a, 0, 0, 0);
        a = __builtin_amdgcn_mfma_f32_16x16x32_bf16(whi, xmi, a, 0, 0, 0);
        a = __builtin_amdgcn_mfma_f32_16x16x32_bf16(wmi, xhi, a, 0, 0, 0);
        a = __builtin_amdgcn_mfma_f32_16x16x32_bf16(whi, xlo, a, 0, 0, 0);
        a = __builtin_amdgcn_mfma_f32_16x16x32_bf16(wlo, xhi, a, 0, 0, 0);
        a = __builtin_amdgcn_mfma_f32_16x16x32_bf16(wmi, xmi, a, 0, 0, 0);
        acc[tloc] = a;
      }
    }
    xa = xna; xb = xnb;

    if constexpr (IT == 0) {
#pragma unroll
      for (int tl = 0; tl < 8; ++tl) sreg[tl] += acc[tl] * 0.03125f;
    } else {
      float bup[4];
#pragma unroll
      for (int j = 0; j < 4; ++j) {
        f32x4 p = acc[2 * j] * vfrag[2 * j] + acc[2 * j + 1] * vfrag[2 * j + 1];
        float v = p[0] + p[1] + p[2] + p[3];
        v += __shfl_xor(v, 16);
        v += __shfl_xor(v, 32);
        bup[j] = v;
      }
      if (l < 16) {
#pragma unroll
        for (int j = 0; j < 4; ++j) bl[l * 32 + w * 4 + j] = bup[j];
      }
      BARLDS();
      {
        const int bo = t >> 5, oo = t & 31;
        float lg = bl[bo * 32 + oo];
        if constexpr (IT == 2)
          lg += bbuf[(size_t)(b0 + bo) * (NI * NO) + (size_t)i * NO + oo];
        if constexpr (IT == 1)
          bbuf[(size_t)(b0 + bo) * (NI * NO) + (size_t)i * NO + oo] = lg;
        float mx = lg;
#pragma unroll
        for (int m = 1; m < 32; m <<= 1) mx = fmaxf(mx, __shfl_xor(mx, m));
        const float e = __expf(lg - mx);
        float sm = e;
#pragma unroll
        for (int m = 1; m < 32; m <<= 1) sm += __shfl_xor(sm, m);
        bl[bo * 32 + oo] = e / sm;
      }
      BARLDS();
#pragma unroll
      for (int j = 0; j < 4; ++j) {
        const float cj = bl[(l & 15) * 32 + w * 4 + j];
        sreg[2 * j]     += acc[2 * j]     * cj;
        sreg[2 * j + 1] += acc[2 * j + 1] * cj;
      }
    }
  }

  WAITV(0);
  {
    float* op = spart + ((size_t)ib * NBB + bb) * 16384 + w * 2048 + l * 4;
#pragma unroll
    for (int tl = 0; tl < 8; ++tl) *(f32x4*)(op + tl * 256) = sreg[tl];
  }
}

// ======================= shared small kernels ===============================

__global__ __launch_bounds__(256)
void caps_red(const float* __restrict__ spart, float* __restrict__ s,
              float* __restrict__ part)
{
  const int t = threadIdx.x;
  const size_t e = (size_t)blockIdx.x * 256 + t;
  float a = 0.f;
#pragma unroll
  for (int ibk = 0; ibk < NIB; ++ibk) a += spart[(size_t)ibk * (NBATCH * 1024) + e];
  s[e] = a;
  float qv = a * a;
#pragma unroll
  for (int m = 1; m < 64; m <<= 1) qv += __shfl_xor(qv, m);
  __shared__ float red[4];
  if ((t & 63) == 0) red[t >> 6] = qv;
  __syncthreads();
  if (t == 0) part[blockIdx.x] = red[0] + red[1] + red[2] + red[3];
}

__global__ __launch_bounds__(256)
void caps_norm(const float* __restrict__ part, float* __restrict__ fsc)
{
  const int t = threadIdx.x;
  float qv = part[t] + part[t + 256];
#pragma unroll
  for (int m = 1; m < 64; m <<= 1) qv += __shfl_xor(qv, m);
  __shared__ float red[4];
  if ((t & 63) == 0) red[t >> 6] = qv;
  __syncthreads();
  if (t == 0) {
    const float S = red[0] + red[1] + red[2] + red[3];
    fsc[0] = sqrtf(S) / (1.f + S);
  }
}

__global__ __launch_bounds__(256)
void caps_out(const float* __restrict__ s, const float* __restrict__ fsc,
              float* __restrict__ out)
{
  const int E = blockIdx.x * 256 + threadIdx.x;
  const float v = s[E] * fsc[0];
  const int r = E & 3, ll = (E >> 2) & 63, tl = (E >> 8) & 7,
            w = (E >> 11) & 7, bb = E >> 14;
  const int b = bb * 16 + (ll & 15);
  const int od = w * 128 + tl * 16 + (ll >> 4) * 4 + r;
  out[b * 1024 + od] = v;
}

// ======================= host ==============================================

extern "C" void kernel_launch(void* const* d_in, const int* in_sizes, int n_in,
                              void* d_out, int out_size, void* d_ws, size_t ws_size,
                              hipStream_t stream)
{
  const float* xg = (const float*)d_in[0];
  const float* Wg = (const float*)d_in[1];
  float* out = (float*)d_out;

  // fast ws: P0,P1,P2 (3 x 75,497,472 B) | spart | S | part | fsc(pad) | bbuf
  const size_t planeE  = 4718592;                    // short8v per plane
  const size_t bbufFl  = (size_t)NBATCH * NI * NO;   // 4,718,592 floats
  const size_t need_fast = planeE * 3 * 16 +
      ((size_t)NIB * NBB * 16384 + 131072 + 512 + 4 + bbufFl) * 4;

  if (ws_size >= need_fast) {
    short8v* P0 = (short8v*)d_ws;
    short8v* P1 = P0 + planeE;
    short8v* P2 = P1 + planeE;
    float* spart = (float*)(P2 + planeE);
    float* S    = spart + (size_t)NIB * NBB * 16384;
    float* part = S + 131072;
    float* fsc  = part + 512;
    float* bbuf = fsc + 4;

    dim3 pg(NIB, NBB);
    caps_pack3<<<18432, 256, 0, stream>>>(Wg, P0, P1, P2);

    caps_passd<0><<<pg, 512, 0, stream>>>(xg, P0, P1, P2, spart, S, fsc, bbuf);
    caps_red <<<512, 256, 0, stream>>>(spart, S, part);
    caps_norm<<<1,   256, 0, stream>>>(part, fsc);

    caps_passd<1><<<pg, 512, 0, stream>>>(xg, P0, P1, P2, spart, S, fsc, bbuf);
    caps_red <<<512, 256, 0, stream>>>(spart, S, part);
    caps_norm<<<1,   256, 0, stream>>>(part, fsc);

    caps_passd<2><<<pg, 512, 0, stream>>>(xg, P0, P1, P2, spart, S, fsc, bbuf);
    caps_red <<<512, 256, 0, stream>>>(spart, S, part);
    caps_norm<<<1,   256, 0, stream>>>(part, fsc);

    caps_out <<<512, 256, 0, stream>>>(S, fsc, out);
  } else {
    // round-6 proven path
    float* wsf   = (float*)d_ws;
    float* spart = wsf;
    float* S     = spart + (size_t)NIB * NBATCH * 1024;
    float* part  = S + (size_t)NBATCH * 1024;
    float* fsc   = part + 512;
    float* bbuf  = fsc + 1;

    const int ldsB = LDS_FLOATS_S * 4;
    (void)hipFuncSetAttribute(reinterpret_cast<const void*>(&caps_pass_s<0>),
                              hipFuncAttributeMaxDynamicSharedMemorySize, ldsB);
    (void)hipFuncSetAttribute(reinterpret_cast<const void*>(&caps_pass_s<1>),
                              hipFuncAttributeMaxDynamicSharedMemorySize, ldsB);
    (void)hipFuncSetAttribute(reinterpret_cast<const void*>(&caps_pass_s<2>),
                              hipFuncAttributeMaxDynamicSharedMemorySize, ldsB);

    dim3 pg(NIB, NBB);
    caps_pass_s<0><<<pg, 512, ldsB, stream>>>(xg, Wg, spart, S, fsc, bbuf);
    caps_red <<<512, 256, 0, stream>>>(spart, S, part);
    caps_norm<<<1,   256, 0, stream>>>(part, fsc);

    caps_pass_s<1><<<pg, 512, ldsB, stream>>>(xg, Wg, spart, S, fsc, bbuf);
    caps_red <<<512, 256, 0, stream>>>(spart, S, part);
    caps_norm<<<1,   256, 0, stream>>>(part, fsc);

    caps_pass_s<2><<<pg, 512, ldsB, stream>>>(xg, Wg, spart, S, fsc, bbuf);
    caps_red <<<512, 256, 0, stream>>>(spart, S, part);
    caps_norm<<<1,   256, 0, stream>>>(part, fsc);

    caps_out <<<512, 256, 0, stream>>>(S, fsc, out);
  }
}

// Round 12
// 690.330 us; speedup vs baseline: 1.1275x; 1.1275x over previous
//
#include <hip/hip_runtime.h>
#include <math.h>

// Problem constants
#define NI 1152
#define NO 32
#define DI 32
#define DO 32
#define NBATCH 128

constexpr int IBLK = 36;                 // i's per block
constexpr int NIB  = 32;                 // i-blocks
constexpr int BBLK = 16;                 // batches per block
constexpr int NBB  = NBATCH / BBLK;      // 8

typedef __attribute__((ext_vector_type(8))) short short8v;
typedef __attribute__((ext_vector_type(4))) float f32x4;
typedef __attribute__((ext_vector_type(2))) float f32x2;

#define BARLDS() do { asm volatile("s_waitcnt lgkmcnt(0)" ::: "memory"); \
  __builtin_amdgcn_sched_barrier(0); __builtin_amdgcn_s_barrier(); } while (0)

// 3-way truncation split: w = hi + mid + lo (bf16 each), residual <= 2^-23|w|.
struct S3 { short hi, mi, lo; };
__device__ __forceinline__ S3 split3(float w) {
  S3 r;
  const unsigned u = __float_as_uint(w);
  r.hi = (short)(u >> 16);
  const float r1 = w - __uint_as_float(u & 0xFFFF0000u);
  const unsigned r1u = __float_as_uint(r1);
  r.mi = (short)(r1u >> 16);
  const float r2 = r1 - __uint_as_float(r1u & 0xFFFF0000u);
  r.lo = (short)(__float_as_uint(r2) >> 16);
  return r;
}

// ============ FAST PATH: identity planes + 16-wave pipelined pass ==========

// Identity pack: plane short index j holds limb of Wg flat float index j.
__global__ __launch_bounds__(256)
void caps_pack3(const float* __restrict__ Wg, short8v* __restrict__ P0,
                short8v* __restrict__ P1, short8v* __restrict__ P2)
{
  const size_t j8 = (size_t)blockIdx.x * 256 + threadIdx.x;
  const float* src = Wg + j8 * 8;
  const f32x4 a = *(const f32x4*)src;
  const f32x4 b = *(const f32x4*)(src + 4);
  short8v hi, mi, lo;
#pragma unroll
  for (int e = 0; e < 4; ++e) {
    S3 r0 = split3(a[e]); hi[e] = r0.hi;     mi[e] = r0.mi;     lo[e] = r0.lo;
    S3 r1 = split3(b[e]); hi[4 + e] = r1.hi; mi[4 + e] = r1.mi; lo[4 + e] = r1.lo;
  }
  P0[j8] = hi;
  P1[j8] = mi;
  P2[j8] = lo;
}

// One routing iteration. 1024 threads = 16 waves, 4 od-tiles per wave.
// Lane l, tile tl of wave w holds W[i][od = w*64 + tl*16 + (l&15)][k=(l>>4)*8+e]
// -> plane short8v index = i*4096 + od*4 + (l>>4).
//  IT==0: sreg IS the MFMA accumulator over all i; c=1/32 applied at flush.
//  IT==1: logits = sum_d x_hat*v0 ; write to bbuf ; softmax ; s1 partials.
//  IT==2: logits = bbuf + sum_d x_hat*v1 ; softmax ; s2 partials.
template<int IT>
__global__ __launch_bounds__(1024, 4)
void caps_passe(const float* __restrict__ xg, const short8v* __restrict__ P0,
                const short8v* __restrict__ P1, const short8v* __restrict__ P2,
                float* __restrict__ spart, const float* __restrict__ s_in,
                const float* __restrict__ fsc, float* __restrict__ bbuf)
{
  __shared__ float bl[16 * 32];

  const int t = threadIdx.x, w = t >> 6, l = t & 63;
  const int ib = blockIdx.x, bb = blockIdx.y, b0 = bb * BBLK;

  // x fragment source: x[b = l&15][k = (l>>4)*8 + e]
  const float* xbase = xg + (size_t)(b0 + (l & 15)) * (NI * DI) + (l >> 4) * 8;

  // per-lane W fragment base (short8v units), tile stride 64
  const size_t wbase = (size_t)(w * 64 + (l & 15)) * 4 + (l >> 4);

  // v fragments (IT>0): v = f * s_in, flat fragment layout
  f32x4 vfrag[4];
  if constexpr (IT > 0) {
    const float f = fsc[0];
    const float* vp = s_in + (size_t)bb * 16384 + w * 1024 + l * 4;
#pragma unroll
    for (int tl = 0; tl < 4; ++tl) {
      f32x4 sv = *(const f32x4*)(vp + tl * 256);
      vfrag[tl] = sv * f;
    }
  }

  f32x4 sreg[4];
#pragma unroll
  for (int tl = 0; tl < 4; ++tl) sreg[tl] = (f32x4){0.f, 0.f, 0.f, 0.f};

  const int i0 = ib * IBLK;

  // rolling register buffer: one full i of W fragments (12 short8v, in flight)
  short8v W0[4], W1[4], W2[4];
  {
    const size_t pb = (size_t)i0 * 4096 + wbase;
#pragma unroll
    for (int tl = 0; tl < 4; ++tl) {
      const size_t idx = pb + (size_t)tl * 64;
      W0[tl] = P0[idx]; W1[tl] = P1[idx]; W2[tl] = P2[idx];
    }
  }

  for (int ii = 0; ii < IBLK; ++ii) {
    const int i = i0 + ii;
    const int inext = i0 + ((ii + 1 < IBLK) ? ii + 1 : ii);  // uniform tail

    // x load + 3-limb split
    const f32x4 xa = *(const f32x4*)(xbase + (size_t)i * DI);
    const f32x4 xb = *(const f32x4*)(xbase + (size_t)i * DI + 4);
    short8v xhi, xmi, xlo;
#pragma unroll
    for (int e = 0; e < 4; ++e) {
      S3 r0 = split3(xa[e]);
      xhi[e] = r0.hi; xmi[e] = r0.mi; xlo[e] = r0.lo;
      S3 r1 = split3(xb[e]);
      xhi[4 + e] = r1.hi; xmi[4 + e] = r1.mi; xlo[4 + e] = r1.lo;
    }

    f32x4 acc[4];
    if constexpr (IT > 0) {
#pragma unroll
      for (int tl = 0; tl < 4; ++tl) acc[tl] = (f32x4){0.f, 0.f, 0.f, 0.f};
    }

    const size_t pn = (size_t)inext * 4096 + wbase;
#pragma unroll
    for (int tl = 0; tl < 4; ++tl) {
      const short8v wh = W0[tl];
      const short8v wm = W1[tl];
      const short8v wo = W2[tl];
      const size_t idx = pn + (size_t)tl * 64;
      W0[tl] = P0[idx]; W1[tl] = P1[idx]; W2[tl] = P2[idx];  // refill i+1

      f32x4 a = (IT == 0) ? sreg[tl] : acc[tl];
      a = __builtin_amdgcn_mfma_f32_16x16x32_bf16(wh, xhi, a, 0, 0, 0);
      a = __builtin_amdgcn_mfma_f32_16x16x32_bf16(wh, xmi, a, 0, 0, 0);
      a = __builtin_amdgcn_mfma_f32_16x16x32_bf16(wm, xhi, a, 0, 0, 0);
      a = __builtin_amdgcn_mfma_f32_16x16x32_bf16(wh, xlo, a, 0, 0, 0);
      a = __builtin_amdgcn_mfma_f32_16x16x32_bf16(wo, xhi, a, 0, 0, 0);
      a = __builtin_amdgcn_mfma_f32_16x16x32_bf16(wm, xmi, a, 0, 0, 0);
      if constexpr (IT == 0) sreg[tl] = a; else acc[tl] = a;
    }

    // ---- routing ----
    if constexpr (IT > 0) {
      // lane holds x_hat rows od = w*64 + tl*16 + (l>>4)*4 + r, col b = l&15.
      // o = 2w + j, j in {0,1} covering tiles {2j, 2j+1}.
      float bup[2];
#pragma unroll
      for (int j = 0; j < 2; ++j) {
        f32x4 p = acc[2 * j] * vfrag[2 * j] + acc[2 * j + 1] * vfrag[2 * j + 1];
        float v = p[0] + p[1] + p[2] + p[3];
        v += __shfl_xor(v, 16);
        v += __shfl_xor(v, 32);
        bup[j] = v;
      }
      if (l < 16) {
#pragma unroll
        for (int j = 0; j < 2; ++j) bl[l * 32 + w * 2 + j] = bup[j];
      }
      BARLDS();
      if (t < 512) {  // softmax over o: thread -> (b = t>>5, o = t&31)
        const int bo = t >> 5, oo = t & 31;
        float lg = bl[bo * 32 + oo];
        if constexpr (IT == 2)
          lg += bbuf[(size_t)(b0 + bo) * (NI * NO) + (size_t)i * NO + oo];
        if constexpr (IT == 1)
          bbuf[(size_t)(b0 + bo) * (NI * NO) + (size_t)i * NO + oo] = lg;
        float mx = lg;
#pragma unroll
        for (int m = 1; m < 32; m <<= 1) mx = fmaxf(mx, __shfl_xor(mx, m));
        const float e = __expf(lg - mx);
        float sm = e;
#pragma unroll
        for (int m = 1; m < 32; m <<= 1) sm += __shfl_xor(sm, m);
        bl[bo * 32 + oo] = e / sm;
      }
      BARLDS();
#pragma unroll
      for (int j = 0; j < 2; ++j) {
        const float cj = bl[(l & 15) * 32 + w * 2 + j];
        sreg[2 * j]     += acc[2 * j]     * cj;
        sreg[2 * j + 1] += acc[2 * j + 1] * cj;
      }
    }
  }

  // flush partials: flat layout slab + w*1024 + tl*256 + l*4
  {
    float* op = spart + ((size_t)ib * NBB + bb) * 16384 + w * 1024 + l * 4;
#pragma unroll
    for (int tl = 0; tl < 4; ++tl) {
      f32x4 o = sreg[tl];
      if constexpr (IT == 0) o = o * 0.03125f;
      *(f32x4*)(op + tl * 256) = o;
    }
  }
}

// ======================= SLOW PATH (round-6, proven) ========================

constexpr int LDS_FLOATS_S = 32 * 1024 + 16 * 32;

__device__ __forceinline__ void gll16(const float* g, float* l) {
  __builtin_amdgcn_global_load_lds(
      (const __attribute__((address_space(1))) void*)(const void*)g,
      (__attribute__((address_space(3))) void*)(void*)l, 16, 0, 0);
}

#define WAITV(n) do { asm volatile("s_waitcnt vmcnt(" #n ")" ::: "memory"); \
  __builtin_amdgcn_sched_barrier(0); } while (0)
#define LGKM0() do { asm volatile("s_waitcnt lgkmcnt(0)" ::: "memory"); \
  __builtin_amdgcn_sched_barrier(0); } while (0)

__device__ __forceinline__ void stage_w_half(const float* __restrict__ Wg,
                                             float* __restrict__ Wt,
                                             int i, int h, int w, size_t wsrc_lane) {
  const float* sb = Wg + (size_t)i * 32768 + wsrc_lane + (size_t)h * 2048;
  float* db = Wt + (size_t)(w * 1024 + h * 512) * 4;
#pragma unroll
  for (int r = 0; r < 8; ++r)
    gll16(sb + r * 256, db + r * 256);
}

template<int IT>
__global__ __launch_bounds__(512, 2)
void caps_pass_s(const float* __restrict__ xg, const float* __restrict__ Wg,
                 float* __restrict__ spart, const float* __restrict__ s_in,
                 const float* __restrict__ fsc, float* __restrict__ bbuf)
{
  extern __shared__ float lds[];
  float* Wt = lds;
  float* bl = lds + 32 * 1024;

  const int t = threadIdx.x, w = t >> 6, l = t & 63;
  const int ib = blockIdx.x, bb = blockIdx.y, b0 = bb * BBLK;

  const size_t wsrc_lane = (size_t)(w * 128 + (l >> 3)) * 32
                         + (size_t)(((l & 7) ^ (l >> 3)) * 4);
  int colf[4];
#pragma unroll
  for (int s = 0; s < 4; ++s)
    colf[s] = ((((l >> 4) * 2 + (s >> 1)) ^ (l & 7)) * 4) + (s & 1) * 2;

  const float* xbase = xg + (size_t)(b0 + (l & 15)) * (NI * DI) + (l >> 4) * 8;

  f32x4 vfrag[8];
  if constexpr (IT > 0) {
    const float f = fsc[0];
    const float* vp = s_in + (size_t)bb * 16384 + w * 2048 + l * 4;
#pragma unroll
    for (int tl = 0; tl < 8; ++tl) {
      f32x4 sv = *(const f32x4*)(vp + tl * 256);
      vfrag[tl] = sv * f;
    }
  }
  WAITV(0);

  f32x4 sreg[8];
#pragma unroll
  for (int tl = 0; tl < 8; ++tl) sreg[tl] = (f32x4){0.f, 0.f, 0.f, 0.f};

  const int i0 = ib * IBLK;
  stage_w_half(Wg, Wt, i0, 0, w, wsrc_lane);
  f32x4 xa = *(const f32x4*)(xbase + (size_t)i0 * DI);
  f32x4 xb = *(const f32x4*)(xbase + (size_t)i0 * DI + 4);
  stage_w_half(Wg, Wt, i0, 1, w, wsrc_lane);

  for (int ii = 0; ii < IBLK; ++ii) {
    const int i = i0 + ii;
    const int inext = i0 + ((ii + 1 < IBLK) ? ii + 1 : ii);

    f32x4 acc[8];
#pragma unroll
    for (int tl = 0; tl < 8; ++tl) acc[tl] = (f32x4){0.f, 0.f, 0.f, 0.f};

    short8v xhi, xmi, xlo;
    f32x4 xna, xnb;

#pragma unroll
    for (int h = 0; h < 2; ++h) {
      f32x2 wf[4][4];
      if (h == 0) {
        WAITV(8);
#pragma unroll
        for (int e = 0; e < 4; ++e) {
          S3 sa = split3(xa[e]);
          xhi[e] = sa.hi; xmi[e] = sa.mi; xlo[e] = sa.lo;
          S3 sb2 = split3(xb[e]);
          xhi[4 + e] = sb2.hi; xmi[4 + e] = sb2.mi; xlo[4 + e] = sb2.lo;
        }
      } else {
        WAITV(10);
      }
#pragma unroll
      for (int tl = 0; tl < 4; ++tl) {
        const float* rp = Wt + (size_t)(w * 128 + (h * 4 + tl) * 16 + (l & 15)) * 32;
#pragma unroll
        for (int s = 0; s < 4; ++s) wf[tl][s] = *(const f32x2*)(rp + colf[s]);
      }
      LGKM0();

      if (h == 0) {
        stage_w_half(Wg, Wt, inext, 0, w, wsrc_lane);
        xna = *(const f32x4*)(xbase + (size_t)inext * DI);
        xnb = *(const f32x4*)(xbase + (size_t)inext * DI + 4);
      } else {
        stage_w_half(Wg, Wt, inext, 1, w, wsrc_lane);
      }

#pragma unroll
      for (int tl = 0; tl < 4; ++tl) {
        const int tloc = h * 4 + tl;
        short8v whi, wmi, wlo;
#pragma unroll
        for (int s = 0; s < 4; ++s) {
          S3 s0 = split3(wf[tl][s].x);
          whi[2 * s] = s0.hi; wmi[2 * s] = s0.mi; wlo[2 * s] = s0.lo;
          S3 s1 = split3(wf[tl][s].y);
          whi[2 * s + 1] = s1.hi; wmi[2 * s + 1] = s1.mi; wlo[2 * s + 1] = s1.lo;
        }
        f32x4 a = acc[tloc];
        a = __builtin_amdgcn_mfma_f32_16x16x32_bf16(whi, xhi, a, 0, 0, 0);
        a = __builtin_amdgcn_mfma_f32_16x16x32_bf16(whi, xmi, a, 0, 0, 0);
        a = __builtin_amdgcn_mfma_f32_16x16x32_bf16(wmi, xhi, a, 0, 0, 0);
        a = __builtin_amdgcn_mfma_f32_16x16x32_bf16(whi, xlo, a, 0, 0, 0);
        a = __builtin_amdgcn_mfma_f32_16x16x32_bf16(wlo, xhi, a, 0, 0, 0);
        a = __builtin_amdgcn_mfma_f32_16x16x32_bf16(wmi, xmi, a, 0, 0, 0);
        acc[tloc] = a;
      }
    }
    xa = xna; xb = xnb;

    if constexpr (IT == 0) {
#pragma unroll
      for (int tl = 0; tl < 8; ++tl) sreg[tl] += acc[tl] * 0.03125f;
    } else {
      float bup[4];
#pragma unroll
      for (int j = 0; j < 4; ++j) {
        f32x4 p = acc[2 * j] * vfrag[2 * j] + acc[2 * j + 1] * vfrag[2 * j + 1];
        float v = p[0] + p[1] + p[2] + p[3];
        v += __shfl_xor(v, 16);
        v += __shfl_xor(v, 32);
        bup[j] = v;
      }
      if (l < 16) {
#pragma unroll
        for (int j = 0; j < 4; ++j) bl[l * 32 + w * 4 + j] = bup[j];
      }
      BARLDS();
      {
        const int bo = t >> 5, oo = t & 31;
        float lg = bl[bo * 32 + oo];
        if constexpr (IT == 2)
          lg += bbuf[(size_t)(b0 + bo) * (NI * NO) + (size_t)i * NO + oo];
        if constexpr (IT == 1)
          bbuf[(size_t)(b0 + bo) * (NI * NO) + (size_t)i * NO + oo] = lg;
        float mx = lg;
#pragma unroll
        for (int m = 1; m < 32; m <<= 1) mx = fmaxf(mx, __shfl_xor(mx, m));
        const float e = __expf(lg - mx);
        float sm = e;
#pragma unroll
        for (int m = 1; m < 32; m <<= 1) sm += __shfl_xor(sm, m);
        bl[bo * 32 + oo] = e / sm;
      }
      BARLDS();
#pragma unroll
      for (int j = 0; j < 4; ++j) {
        const float cj = bl[(l & 15) * 32 + w * 4 + j];
        sreg[2 * j]     += acc[2 * j]     * cj;
        sreg[2 * j + 1] += acc[2 * j + 1] * cj;
      }
    }
  }

  WAITV(0);
  {
    float* op = spart + ((size_t)ib * NBB + bb) * 16384 + w * 2048 + l * 4;
#pragma unroll
    for (int tl = 0; tl < 8; ++tl) *(f32x4*)(op + tl * 256) = sreg[tl];
  }
}

// ======================= shared small kernels ===============================

__global__ __launch_bounds__(256)
void caps_red(const float* __restrict__ spart, float* __restrict__ s,
              float* __restrict__ part)
{
  const int t = threadIdx.x;
  const size_t e = (size_t)blockIdx.x * 256 + t;
  float a = 0.f;
#pragma unroll
  for (int ibk = 0; ibk < NIB; ++ibk) a += spart[(size_t)ibk * (NBATCH * 1024) + e];
  s[e] = a;
  float qv = a * a;
#pragma unroll
  for (int m = 1; m < 64; m <<= 1) qv += __shfl_xor(qv, m);
  __shared__ float red[4];
  if ((t & 63) == 0) red[t >> 6] = qv;
  __syncthreads();
  if (t == 0) part[blockIdx.x] = red[0] + red[1] + red[2] + red[3];
}

__global__ __launch_bounds__(256)
void caps_norm(const float* __restrict__ part, float* __restrict__ fsc)
{
  const int t = threadIdx.x;
  float qv = part[t] + part[t + 256];
#pragma unroll
  for (int m = 1; m < 64; m <<= 1) qv += __shfl_xor(qv, m);
  __shared__ float red[4];
  if ((t & 63) == 0) red[t >> 6] = qv;
  __syncthreads();
  if (t == 0) {
    const float S = red[0] + red[1] + red[2] + red[3];
    fsc[0] = sqrtf(S) / (1.f + S);
  }
}

// Decode 16-wave flat layout -> [b][od]
__global__ __launch_bounds__(256)
void caps_out16(const float* __restrict__ s, const float* __restrict__ fsc,
                float* __restrict__ out)
{
  const int E = blockIdx.x * 256 + threadIdx.x;
  const float v = s[E] * fsc[0];
  const int r = E & 3, ll = (E >> 2) & 63, tl = (E >> 8) & 3,
            w = (E >> 10) & 15, bb = E >> 14;
  const int b = bb * 16 + (ll & 15);
  const int od = w * 64 + tl * 16 + (ll >> 4) * 4 + r;
  out[b * 1024 + od] = v;
}

// Decode 8-wave flat layout -> [b][od] (slow path)
__global__ __launch_bounds__(256)
void caps_out(const float* __restrict__ s, const float* __restrict__ fsc,
              float* __restrict__ out)
{
  const int E = blockIdx.x * 256 + threadIdx.x;
  const float v = s[E] * fsc[0];
  const int r = E & 3, ll = (E >> 2) & 63, tl = (E >> 8) & 7,
            w = (E >> 11) & 7, bb = E >> 14;
  const int b = bb * 16 + (ll & 15);
  const int od = w * 128 + tl * 16 + (ll >> 4) * 4 + r;
  out[b * 1024 + od] = v;
}

// ======================= host ==============================================

extern "C" void kernel_launch(void* const* d_in, const int* in_sizes, int n_in,
                              void* d_out, int out_size, void* d_ws, size_t ws_size,
                              hipStream_t stream)
{
  const float* xg = (const float*)d_in[0];
  const float* Wg = (const float*)d_in[1];
  float* out = (float*)d_out;

  // fast ws: P0,P1,P2 (3 x 75,497,472 B) | spart | S | part | fsc(pad) | bbuf
  const size_t planeE  = 4718592;                    // short8v per plane
  const size_t bbufFl  = (size_t)NBATCH * NI * NO;   // 4,718,592 floats
  const size_t need_fast = planeE * 3 * 16 +
      ((size_t)NIB * NBB * 16384 + 131072 + 512 + 4 + bbufFl) * 4;

  if (ws_size >= need_fast) {
    short8v* P0 = (short8v*)d_ws;
    short8v* P1 = P0 + planeE;
    short8v* P2 = P1 + planeE;
    float* spart = (float*)(P2 + planeE);
    float* S    = spart + (size_t)NIB * NBB * 16384;
    float* part = S + 131072;
    float* fsc  = part + 512;
    float* bbuf = fsc + 4;

    dim3 pg(NIB, NBB);
    caps_pack3<<<18432, 256, 0, stream>>>(Wg, P0, P1, P2);

    caps_passe<0><<<pg, 1024, 0, stream>>>(xg, P0, P1, P2, spart, S, fsc, bbuf);
    caps_red <<<512, 256, 0, stream>>>(spart, S, part);
    caps_norm<<<1,   256, 0, stream>>>(part, fsc);

    caps_passe<1><<<pg, 1024, 0, stream>>>(xg, P0, P1, P2, spart, S, fsc, bbuf);
    caps_red <<<512, 256, 0, stream>>>(spart, S, part);
    caps_norm<<<1,   256, 0, stream>>>(part, fsc);

    caps_passe<2><<<pg, 1024, 0, stream>>>(xg, P0, P1, P2, spart, S, fsc, bbuf);
    caps_red <<<512, 256, 0, stream>>>(spart, S, part);
    caps_norm<<<1,   256, 0, stream>>>(part, fsc);

    caps_out16<<<512, 256, 0, stream>>>(S, fsc, out);
  } else {
    // round-6 proven path
    float* wsf   = (float*)d_ws;
    float* spart = wsf;
    float* S     = spart + (size_t)NIB * NBATCH * 1024;
    float* part  = S + (size_t)NBATCH * 1024;
    float* fsc   = part + 512;
    float* bbuf  = fsc + 1;

    const int ldsB = LDS_FLOATS_S * 4;
    (void)hipFuncSetAttribute(reinterpret_cast<const void*>(&caps_pass_s<0>),
                              hipFuncAttributeMaxDynamicSharedMemorySize, ldsB);
    (void)hipFuncSetAttribute(reinterpret_cast<const void*>(&caps_pass_s<1>),
                              hipFuncAttributeMaxDynamicSharedMemorySize, ldsB);
    (void)hipFuncSetAttribute(reinterpret_cast<const void*>(&caps_pass_s<2>),
                              hipFuncAttributeMaxDynamicSharedMemorySize, ldsB);

    dim3 pg(NIB, NBB);
    caps_pass_s<0><<<pg, 512, ldsB, stream>>>(xg, Wg, spart, S, fsc, bbuf);
    caps_red <<<512, 256, 0, stream>>>(spart, S, part);
    caps_norm<<<1,   256, 0, stream>>>(part, fsc);

    caps_pass_s<1><<<pg, 512, ldsB, stream>>>(xg, Wg, spart, S, fsc, bbuf);
    caps_red <<<512, 256, 0, stream>>>(spart, S, part);
    caps_norm<<<1,   256, 0, stream>>>(part, fsc);

    caps_pass_s<2><<<pg, 512, ldsB, stream>>>(xg, Wg, spart, S, fsc, bbuf);
    caps_red <<<512, 256, 0, stream>>>(spart, S, part);
    caps_norm<<<1,   256, 0, stream>>>(part, fsc);

    caps_out <<<512, 256, 0, stream>>>(S, fsc, out);
  }
}